// Round 8
// baseline (332.396 us; speedup 1.0000x reference)
//
#include <hip/hip_runtime.h>
#include <hip/hip_bf16.h>

// MaskMLP R11: modules_fused reverted to R4 (best measured, 83us; the R6/R9/
// R10 levers -- occupancy, LDS shrink, barrier removal -- all measured worse).
// gemm_l0 rebuilt 128x64 -> 128x128 tile (m93/m97 structure): doubles MFMA
// per barrier-round (16->32, ~260cy latency cover), halves A re-reads
// (64->32 c0-blocks), grid 512 -> 256 blocks = 1/CU. BK=64 dist-2, 16 loads
// in flight, WAITV(8). cvt_all unchanged.

using bf16 = __hip_bfloat16;
typedef short bf16x8 __attribute__((ext_vector_type(8)));   // 8 bf16 = 4 VGPRs
typedef float f32x4 __attribute__((ext_vector_type(4)));

constexpr int B_ = 1024;   // batch
constexpr int M_ = 128;    // modules

#define WAITV(N) asm volatile("s_waitcnt vmcnt(" #N ")" ::: "memory")
#define WAITL()  asm volatile("s_waitcnt lgkmcnt(0)" ::: "memory")
#define BAR()    asm volatile("s_barrier" ::: "memory")

// async global->LDS, 16B/lane; LDS dest = wave-uniform base + lane*16.
__device__ __forceinline__ void gload16_lds(const bf16* gp, bf16* lp) {
    __builtin_amdgcn_global_load_lds(
        (__attribute__((address_space(1))) void*)const_cast<bf16*>(gp),
        (__attribute__((address_space(3))) void*)lp,
        16, 0, 0);
}

// ---------------- fused fp32 -> bf16 conversion (x, W0..W4) ----------------
struct CvtArgs {
    const float4* src[6];
    short4* dst[6];
};
__global__ void cvt_all(CvtArgs a) {
    constexpr int starts[7] = {0, 1048576, 5242880, 5308416, 5570560,
                               6619136, 10813440};
    int i = blockIdx.x * blockDim.x + threadIdx.x;
    if (i >= starts[6]) return;
    int s = 0;
#pragma unroll
    for (int k = 1; k < 6; ++k) s += (i >= starts[k]) ? 1 : 0;
    int off = i - starts[s];
    float4 v = a.src[s][off];
    union { bf16 h[4]; short4 s4; } u;
    u.h[0] = __float2bfloat16(v.x);
    u.h[1] = __float2bfloat16(v.y);
    u.h[2] = __float2bfloat16(v.z);
    u.h[3] = __float2bfloat16(v.w);
    a.dst[s][off] = u.s4;
}

// ---------------- L0: h0 = relu(x @ W0^T + b0), K=4096 ----------------
// 128x128 tile, BK=64 (two 32-k halves), 2 LDS sets (64KB), prefetch dist-2.
// 4 waves in 2x2 grid, 64x64 out each (acc 4x4). 8 gloads/wave/stage ->
// 16 in flight, WAITV(8) at round entry. Grid (32,8) = 256 blocks = 1/CU.
__global__ __launch_bounds__(256, 2)
void gemm_l0(const bf16* __restrict__ A, const bf16* __restrict__ W,
             const float* __restrict__ bias, bf16* __restrict__ C) {
    constexpr int LDA = 4096;
    __shared__ __align__(16) bf16 sA[2][2][128 * 32];   // [set][half][row*32]
    __shared__ __align__(16) bf16 sB[2][2][128 * 32];

    const int tid = threadIdx.x, w = tid >> 6, lane = tid & 63;
    const int q = lane >> 4, ln = lane & 15;
    const int lr = lane >> 2, lk = lane & 3;
    const int swz = (lk ^ (lr & 3)) * 8;
    const int wm = w >> 1, wn = w & 1;
    const int r0 = blockIdx.y * 128, c0 = blockIdx.x * 128;

    auto stage = [&](int s, int set) {   // 8 gloads/wave
        const int k0 = s * 64;
#pragma unroll
        for (int h = 0; h < 2; ++h)
#pragma unroll
            for (int t = 0; t < 2; ++t) {
                int grp = w * 2 + t;     // 8 groups of 16 rows over 4 waves
                gload16_lds(A + (size_t)(r0 + grp * 16 + lr) * LDA + k0 + h * 32 + swz,
                            &sA[set][h][grp * 512]);
                gload16_lds(W + (size_t)(c0 + grp * 16 + lr) * LDA + k0 + h * 32 + swz,
                            &sB[set][h][grp * 512]);
            }
    };

    f32x4 acc[4][4];
#pragma unroll
    for (int i = 0; i < 4; ++i)
#pragma unroll
        for (int j = 0; j < 4; ++j) acc[i][j] = (f32x4){0.f, 0.f, 0.f, 0.f};

    stage(0, 0);
    stage(1, 1);
    for (int r = 0; r < 64; ++r) {
        if (r < 63) WAITV(8); else WAITV(0);   // current stage arrived
        BAR();
        const int set = r & 1;
        bf16x8 aF[2][4], bF[2][4];
#pragma unroll
        for (int h = 0; h < 2; ++h) {
#pragma unroll
            for (int i = 0; i < 4; ++i) {
                int row = wm * 64 + i * 16 + ln;
                aF[h][i] = *(const bf16x8*)&sA[set][h][row * 32 + ((q ^ (row & 3)) * 8)];
            }
#pragma unroll
            for (int j = 0; j < 4; ++j) {
                int rn = wn * 64 + j * 16 + ln;
                bF[h][j] = *(const bf16x8*)&sB[set][h][rn * 32 + ((q ^ (rn & 3)) * 8)];
            }
        }
        WAITL();
        BAR();                                  // release this set
        if (r + 2 < 64) stage(r + 2, set);      // refill just-freed set
#pragma unroll
        for (int h = 0; h < 2; ++h)
#pragma unroll
            for (int i = 0; i < 4; ++i)
#pragma unroll
                for (int j = 0; j < 4; ++j)
                    acc[i][j] = __builtin_amdgcn_mfma_f32_16x16x32_bf16(
                        aF[h][i], bF[h][j], acc[i][j], 0, 0, 0);
    }

#pragma unroll
    for (int j = 0; j < 4; ++j) {
        int col = c0 + wn * 64 + j * 16 + ln;
        float bv = bias[col];
#pragma unroll
        for (int i = 0; i < 4; ++i)
#pragma unroll
            for (int rr = 0; rr < 4; ++rr) {
                int row = r0 + wm * 64 + i * 16 + q * 4 + rr;
                float v = acc[i][j][rr] + bv;
                v = v > 0.f ? v : 0.f;
                C[(size_t)row * 4096 + col] = __float2bfloat16(v);
            }
    }
}

// ---------------- fused L1..L4 + Wout + sigmoid (R4 version, 83us) ----------
// grid (16 strips, 128 modules), 4 waves. LDS pool (bf16 elems):
//   h3 @0     stride 264, 64 rows -> 16896   (P3 W bufs [0,8192),[8192,16384);
//                                             W1 @8192 during P1)
//   h2 @16896 stride 136 -> 8704             (P4 bufs b0@16896 b1@20992)
//   h1 @25600 stride 72  -> 4608             (P4 buf  b2@25600)
//   h0 @30208 64x32 xor  -> 2048             (logit scratch floats at end)
__global__ __launch_bounds__(256, 2)
void modules_fused(const bf16* __restrict__ h0g,
                   const bf16* __restrict__ W1b, const float* __restrict__ b1,
                   const bf16* __restrict__ W2b, const float* __restrict__ b2,
                   const bf16* __restrict__ W3b, const float* __restrict__ b3,
                   const bf16* __restrict__ W4b, const float* __restrict__ b4,
                   const float* __restrict__ Wout, const float* __restrict__ bout,
                   float* __restrict__ out) {
    constexpr int H3O = 0, H2O = 16896, H1O = 25600, H0O = 30208;
    constexpr int P4B0 = 16896, P4B1 = 20992, P4B2 = 25600;
    __shared__ __align__(16) bf16 pool[32768];

    const int tid = threadIdx.x, w = tid >> 6, lane = tid & 63;
    const int q = lane >> 4, ln = lane & 15;
    const int lr = lane >> 2, lk = lane & 3;
    const int swz = (lk ^ (lr & 3)) * 8;
    const int m = blockIdx.y;
    const int r0 = blockIdx.x * 64;

    const bf16* W1m = W1b + (size_t)m * 64 * 32;
    const bf16* W2m = W2b + (size_t)m * 128 * 64;
    const bf16* W3m = W3b + (size_t)m * 256 * 128;
    const bf16* W4m = W4b + (size_t)m * 512 * 256;

    auto stage = [&](const bf16* G, int ldg, int rows, int nr0, int k0, int woff) {
#pragma unroll
        for (int t = 0; t < rows / 64; ++t) {
            int r = t * 64 + w * 16 + lr;
            gload16_lds(G + (size_t)(nr0 + r) * ldg + k0 + swz,
                        pool + woff + t * 2048 + w * 512);
        }
    };
    auto rdA = [&](int hoff, int stride, int row, int kc) -> bf16x8 {
        return *(const bf16x8*)&pool[hoff + row * stride + kc * 8];
    };
    auto rdA0 = [&](int row) -> bf16x8 {   // h0, xor layout, kc = q
        return *(const bf16x8*)&pool[H0O + row * 32 + ((q ^ (row & 3)) * 8)];
    };
    auto rdB = [&](int woff, int rn) -> bf16x8 {
        return *(const bf16x8*)&pool[woff + rn * 32 + ((q ^ (rn & 3)) * 8)];
    };
    auto wrH = [&](int hoff, int stride, int row, int col, float v) {
        pool[hoff + row * stride + col] = __float2bfloat16(v);
    };

    // ---- preload all epilogue scalars, then drain vmcnt so counts are exact
    float b1v = b1[m * 64 + w * 16 + ln];
    float b2v[2], b3v[4], b4v[4][2], wov[4][2];
#pragma unroll
    for (int j = 0; j < 2; ++j) b2v[j] = b2[m * 128 + w * 32 + j * 16 + ln];
#pragma unroll
    for (int j = 0; j < 4; ++j) b3v[j] = b3[m * 256 + w * 64 + j * 16 + ln];
#pragma unroll
    for (int nc = 0; nc < 4; ++nc)
#pragma unroll
        for (int j = 0; j < 2; ++j) {
            int col = nc * 128 + w * 32 + j * 16 + ln;
            b4v[nc][j] = b4[(size_t)m * 512 + col];
            wov[nc][j] = Wout[(size_t)m * 512 + col];
        }
    float boutv = bout[m];
    WAITV(0);

    // ---- issue: h0 strip (1), W1 (1), P2 s0 (2), P2 s1 (2) -> out=6
    gload16_lds(h0g + (size_t)(r0 + w * 16 + lr) * 4096 + m * 32 + swz,
                pool + H0O + w * 512);
    stage(W1m, 32, 64, 0, 0, 8192);
    stage(W2m, 64, 128, 0, 0, 0);
    stage(W2m, 64, 128, 0, 32, 4096);

    // ================= P1: h1 = relu(h0 @ W1^T + b1) =================
    WAITV(4);   // h0 + W1 arrived; P2 stages remain in flight
    BAR();
    {
        bf16x8 aF[4], bF;
#pragma unroll
        for (int i = 0; i < 4; ++i) aF[i] = rdA0(i * 16 + ln);
        bF = rdB(8192, w * 16 + ln);
        WAITL();
        BAR();
        f32x4 a1[4];
#pragma unroll
        for (int i = 0; i < 4; ++i) {
            a1[i] = (f32x4){0.f, 0.f, 0.f, 0.f};
            a1[i] = __builtin_amdgcn_mfma_f32_16x16x32_bf16(aF[i], bF, a1[i], 0, 0, 0);
        }
        int col = w * 16 + ln;
#pragma unroll
        for (int i = 0; i < 4; ++i)
#pragma unroll
            for (int rr = 0; rr < 4; ++rr) {
                float v = a1[i][rr] + b1v;
                v = v > 0.f ? v : 0.f;
                wrH(H1O, 72, i * 16 + q * 4 + rr, col, v);
            }
        WAITL();
        BAR();   // h1 visible
    }

    // ================= P2: h2 = relu(h1 @ W2^T + b2), 2 rounds =================
    {
        f32x4 a2[4][2];
#pragma unroll
        for (int i = 0; i < 4; ++i)
#pragma unroll
            for (int j = 0; j < 2; ++j) a2[i][j] = (f32x4){0.f, 0.f, 0.f, 0.f};
#pragma unroll
        for (int kr = 0; kr < 2; ++kr) {
            if (kr == 0) WAITV(2); else WAITV(0);
            BAR();
            bf16x8 aF[4], bF[2];
#pragma unroll
            for (int i = 0; i < 4; ++i) aF[i] = rdA(H1O, 72, i * 16 + ln, kr * 4 + q);
#pragma unroll
            for (int j = 0; j < 2; ++j) bF[j] = rdB(kr * 4096, w * 32 + j * 16 + ln);
            WAITL();
            BAR();
            if (kr == 1) {               // P3 s0,s1 (4+4) over consumed P2 bufs
                stage(W3m, 128, 256, 0, 0, 0);
                stage(W3m, 128, 256, 0, 32, 8192);
            }
#pragma unroll
            for (int i = 0; i < 4; ++i)
#pragma unroll
                for (int j = 0; j < 2; ++j)
                    a2[i][j] = __builtin_amdgcn_mfma_f32_16x16x32_bf16(aF[i], bF[j], a2[i][j], 0, 0, 0);
        }
#pragma unroll
        for (int j = 0; j < 2; ++j) {
            int col = w * 32 + j * 16 + ln;
#pragma unroll
            for (int i = 0; i < 4; ++i)
#pragma unroll
                for (int rr = 0; rr < 4; ++rr) {
                    float v = a2[i][j][rr] + b2v[j];
                    v = v > 0.f ? v : 0.f;
                    wrH(H2O, 136, i * 16 + q * 4 + rr, col, v);
                }
        }
        WAITL();
        BAR();   // h2 visible
    }

    // ================= P3: h3 = relu(h2 @ W3^T + b3), 4 rounds, dist-1 =================
    {
        f32x4 a3[4][4];
#pragma unroll
        for (int i = 0; i < 4; ++i)
#pragma unroll
            for (int j = 0; j < 4; ++j) a3[i][j] = (f32x4){0.f, 0.f, 0.f, 0.f};
#pragma unroll
        for (int kr = 0; kr < 4; ++kr) {
            if (kr < 3) WAITV(4); else WAITV(0);
            BAR();
            bf16x8 aF[4], bF[4];
#pragma unroll
            for (int i = 0; i < 4; ++i) aF[i] = rdA(H2O, 136, i * 16 + ln, kr * 4 + q);
#pragma unroll
            for (int j = 0; j < 4; ++j) bF[j] = rdB((kr & 1) * 8192, w * 64 + j * 16 + ln);
            WAITL();
            BAR();
            if (kr == 0)      stage(W3m, 128, 256, 0, 64, 0);       // s2
            else if (kr == 1) stage(W3m, 128, 256, 0, 96, 8192);    // s3
            else if (kr == 3) {                                     // P4 s0,s1
                stage(W4m, 256, 128, 0, 0, P4B0);
                stage(W4m, 256, 128, 0, 32, P4B1);
            }
#pragma unroll
            for (int i = 0; i < 4; ++i)
#pragma unroll
                for (int j = 0; j < 4; ++j)
                    a3[i][j] = __builtin_amdgcn_mfma_f32_16x16x32_bf16(aF[i], bF[j], a3[i][j], 0, 0, 0);
        }
#pragma unroll
        for (int j = 0; j < 4; ++j) {
            int col = w * 64 + j * 16 + ln;
#pragma unroll
            for (int i = 0; i < 4; ++i)
#pragma unroll
                for (int rr = 0; rr < 4; ++rr) {
                    float v = a3[i][j][rr] + b3v[j];
                    v = v > 0.f ? v : 0.f;
                    wrH(H3O, 264, i * 16 + q * 4 + rr, col, v);
                }
        }
        WAITL();
        BAR();   // h3 visible
    }

    // ========== P4: L4 (512 cols in 4 nc-chunks of 128) + Wout dot, dist-2 ==========
    float pl[4][4];
#pragma unroll
    for (int i = 0; i < 4; ++i)
#pragma unroll
        for (int rr = 0; rr < 4; ++rr) pl[i][rr] = 0.f;

#pragma unroll
    for (int nc = 0; nc < 4; ++nc) {
        f32x4 a4[4][2];
#pragma unroll
        for (int i = 0; i < 4; ++i)
#pragma unroll
            for (int j = 0; j < 2; ++j) a4[i][j] = (f32x4){0.f, 0.f, 0.f, 0.f};
#pragma unroll
        for (int kr = 0; kr < 8; ++kr) {
            const int r = nc * 8 + kr;
            if (r + 2 < 32) {   // prefetch into buffer freed after round r-1
                const int r2 = r + 2;
                const int wb2 = (r2 % 3 == 0) ? P4B0 : (r2 % 3 == 1) ? P4B1 : P4B2;
                stage(W4m, 256, 128, (r2 >> 3) * 128, (r2 & 7) * 32, wb2);
            }
            if (r < 30) WAITV(4); else if (r == 30) WAITV(2); else WAITV(0);
            BAR();
            const int wb = (r % 3 == 0) ? P4B0 : (r % 3 == 1) ? P4B1 : P4B2;
            bf16x8 aF[4], bF[2];
#pragma unroll
            for (int i = 0; i < 4; ++i) aF[i] = rdA(H3O, 264, i * 16 + ln, kr * 4 + q);
#pragma unroll
            for (int j = 0; j < 2; ++j) bF[j] = rdB(wb, w * 32 + j * 16 + ln);
            WAITL();
            BAR();
#pragma unroll
            for (int i = 0; i < 4; ++i)
#pragma unroll
                for (int j = 0; j < 2; ++j)
                    a4[i][j] = __builtin_amdgcn_mfma_f32_16x16x32_bf16(aF[i], bF[j], a4[i][j], 0, 0, 0);
        }
#pragma unroll
        for (int j = 0; j < 2; ++j) {
            float bb = b4v[nc][j], wv = wov[nc][j];
#pragma unroll
            for (int i = 0; i < 4; ++i)
#pragma unroll
                for (int rr = 0; rr < 4; ++rr) {
                    float v = a4[i][j][rr] + bb;
                    v = v > 0.f ? v : 0.f;
                    pl[i][rr] += v * wv;
                }
        }
    }

    // ---- reduce: 16 col-lanes via shuffle, 4 waves via LDS, sigmoid store ----
    float* sc = (float*)&pool[H0O];
#pragma unroll
    for (int i = 0; i < 4; ++i)
#pragma unroll
        for (int rr = 0; rr < 4; ++rr) {
            float p = pl[i][rr];
            p += __shfl_xor(p, 1);
            p += __shfl_xor(p, 2);
            p += __shfl_xor(p, 4);
            p += __shfl_xor(p, 8);
            if (ln == 0) sc[w * 64 + i * 16 + q * 4 + rr] = p;
        }
    __syncthreads();   // vmcnt already 0 here; safe
    if (tid < 64) {
        float s = sc[tid] + sc[64 + tid] + sc[128 + tid] + sc[192 + tid];
        float lg = s + boutv;
        out[(size_t)(r0 + tid) * M_ + m] = 1.f / (1.f + __expf(-lg));
    }
}

// ---------------- host ----------------
extern "C" void kernel_launch(void* const* d_in, const int* in_sizes, int n_in,
                              void* d_out, int out_size, void* d_ws, size_t ws_size,
                              hipStream_t stream) {
    const float* x    = (const float*)d_in[0];
    const float* W0   = (const float*)d_in[1];
    const float* b0   = (const float*)d_in[2];
    const float* W1   = (const float*)d_in[3];
    const float* b1   = (const float*)d_in[4];
    const float* W2   = (const float*)d_in[5];
    const float* b2   = (const float*)d_in[6];
    const float* W3   = (const float*)d_in[7];
    const float* b3   = (const float*)d_in[8];
    const float* W4   = (const float*)d_in[9];
    const float* b4   = (const float*)d_in[10];
    const float* Wout = (const float*)d_in[11];
    const float* bout = (const float*)d_in[12];
    float* out = (float*)d_out;

    char* ws = (char*)d_ws;
    size_t off = 0;
    auto alloc = [&](size_t bytes) -> void* {
        off = (off + 255) & ~(size_t)255;
        void* p = ws + off;
        off += bytes;
        return p;
    };
    bf16* W0b = (bf16*)alloc((size_t)4096 * 4096 * 2);
    bf16* W1b = (bf16*)alloc((size_t)M_ * 64 * 32 * 2);
    bf16* W2b = (bf16*)alloc((size_t)M_ * 128 * 64 * 2);
    bf16* W3b = (bf16*)alloc((size_t)M_ * 256 * 128 * 2);
    bf16* W4b = (bf16*)alloc((size_t)M_ * 512 * 256 * 2);
    bf16* xb  = (bf16*)alloc((size_t)B_ * 4096 * 2);
    bf16* h0  = (bf16*)alloc((size_t)B_ * 4096 * 2);   // [B][128][32]

    CvtArgs ca;
    ca.src[0] = (const float4*)x;  ca.dst[0] = (short4*)xb;
    ca.src[1] = (const float4*)W0; ca.dst[1] = (short4*)W0b;
    ca.src[2] = (const float4*)W1; ca.dst[2] = (short4*)W1b;
    ca.src[3] = (const float4*)W2; ca.dst[3] = (short4*)W2b;
    ca.src[4] = (const float4*)W3; ca.dst[4] = (short4*)W3b;
    ca.src[5] = (const float4*)W4; ca.dst[5] = (short4*)W4b;
    cvt_all<<<(10813440 + 255) / 256, 256, 0, stream>>>(ca);

    {
        dim3 g(4096 / 128, B_ / 128, 1);
        gemm_l0<<<g, 256, 0, stream>>>(xb, W0b, b0, h0);
    }
    {
        dim3 g(B_ / 64, M_, 1);
        modules_fused<<<g, 256, 0, stream>>>(h0, W1b, b1, W2b, b2, W3b, b3,
                                             W4b, b4, Wout, bout, out);
    }
}